// Round 5
// baseline (518.937 us; speedup 1.0000x reference)
//
#include <hip/hip_runtime.h>
#include <math.h>

// Problem constants (match reference)
#define NV 8192
#define EV 49152
#define KK 15625

typedef __attribute__((ext_vector_type(8))) short bf16x8;
typedef __attribute__((ext_vector_type(4))) float f32x4;

__device__ __forceinline__ unsigned short bf16rne(float x) {
    unsigned u = __float_as_uint(x);
    unsigned r = u + 0x7FFFu + ((u >> 16) & 1u);
    return (unsigned short)(r >> 16);
}
__device__ __forceinline__ float bf16tof(unsigned short h) {
    return __uint_as_float(((unsigned)h) << 16);
}

__device__ __forceinline__ void edge_frac(const float* __restrict__ pseudo, int e,
                                          float f[3], int lo[3]) {
#pragma unroll
    for (int j = 0; j < 3; ++j) {
        float v = pseudo[e * 3 + j] * 24.0f;
        float fl = floorf(v);
        int l = (int)fl;
        l = l < 0 ? 0 : (l > 23 ? 23 : l);
        lo[j] = l;
        f[j] = v - (float)l;
    }
}

// Prep kernel: transform x -> h0, zero counts, zero agg (NV*64).
__global__ void prep_kernel(const float* __restrict__ x, float* __restrict__ h0,
                            int* __restrict__ counts, float* __restrict__ agg) {
    int gt = blockIdx.x * blockDim.x + threadIdx.x;  // grid = NV*64 threads
    if (gt < NV) {
        const float LC = -0.22703196f, UC = 0.36853024f;
        const float LM = 1.2585511f, UM = 1.648841f;
        const float R = 10.0f;
        float t0 = (x[gt * 2 + 0] - LC) / (UC - LC) * (2.0f * R) - R;
        float t1 = (x[gt * 2 + 1] - LM) / (UM - LM) * (2.0f * R) - R;
        h0[gt * 2 + 0] = fminf(fmaxf(t0, -R), R);
        h0[gt * 2 + 1] = fminf(fmaxf(t1, -R), R);
    }
    if (gt < KK) counts[gt] = 0;
    if (gt < NV * 64) agg[gt] = 0.0f;
}

__global__ void hist_kernel(const float* __restrict__ pseudo, int* __restrict__ counts) {
    int e = blockIdx.x * blockDim.x + threadIdx.x;
    if (e >= EV) return;
    float f[3]; int lo[3];
    edge_frac(pseudo, e, f, lo);
#pragma unroll
    for (int s = 0; s < 8; ++s) {
        int wi = (lo[0] + (s & 1)) + 25 * (lo[1] + ((s >> 1) & 1)) + 625 * (lo[2] + ((s >> 2) & 1));
        atomicAdd(&counts[wi], 1);
    }
}

// single-block exclusive scan over KK bins
__global__ void scan_kernel(const int* __restrict__ counts, int* __restrict__ offsets,
                            int* __restrict__ cursor) {
    __shared__ int sums[256];
    const int CH = 62;  // 256*62 = 15872 >= 15625
    int t = threadIdx.x;
    int base = t * CH;
    int s = 0;
    for (int i = 0; i < CH; ++i) {
        int idx = base + i;
        if (idx < KK) s += counts[idx];
    }
    sums[t] = s;
    __syncthreads();
    for (int d = 1; d < 256; d <<= 1) {
        int v = (t >= d) ? sums[t - d] : 0;
        __syncthreads();
        sums[t] += v;
        __syncthreads();
    }
    int run = (t > 0) ? sums[t - 1] : 0;
    for (int i = 0; i < CH; ++i) {
        int idx = base + i;
        if (idx < KK) {
            offsets[idx] = run;
            cursor[idx] = run;
            run += counts[idx];
        }
    }
    if (t == 255) offsets[KK] = run;
}

// Store (src, b) and dst per sorted pair.
__global__ void scatter_kernel(const float* __restrict__ pseudo, const int* __restrict__ ei,
                               int* __restrict__ cursor,
                               int2* __restrict__ pair_sb, int* __restrict__ pair_dst) {
    int e = blockIdx.x * blockDim.x + threadIdx.x;
    if (e >= EV) return;
    float f[3]; int lo[3];
    edge_frac(pseudo, e, f, lo);
    int src = ei[e];
    int dst = ei[EV + e];
#pragma unroll
    for (int s = 0; s < 8; ++s) {
        float b = ((s & 1) ? f[0] : 1.0f - f[0]) *
                  (((s >> 1) & 1) ? f[1] : 1.0f - f[1]) *
                  (((s >> 2) & 1) ? f[2] : 1.0f - f[2]);
        int wi = (lo[0] + (s & 1)) + 25 * (lo[1] + ((s >> 1) & 1)) + 625 * (lo[2] + ((s >> 2) & 1));
        int pos = atomicAdd(&cursor[wi], 1);
        pair_sb[pos] = make_int2(src, __float_as_int(b));
        pair_dst[pos] = dst;
    }
}

// MFMA conv v5: each bucket's output columns are SPLIT across waves.
// NT = FOUT/16 n-tiles; wave handles one 16-col slice -> B-frags are only
// KT*2 bf16x8 (16 VGPRs), loaded with 16 independent coalesced loads.
// Block of 4 waves covers 4/NT buckets. All f32 math via hi/lo bf16 split
// (3 MFMAs per logical product). No LDS, no __syncthreads.
template <int FIN, int FOUT>
__global__ __launch_bounds__(256) void conv_v5(
    const float* __restrict__ h, const float* __restrict__ W,
    const int* __restrict__ offsets, const int2* __restrict__ pair_sb,
    const int* __restrict__ pair_dst, float* __restrict__ agg) {
    constexpr int KT = FIN / 32;   // k-tiles
    constexpr int NT = FOUT / 16;  // n-tiles (waves per bucket)
    constexpr int BPB = 4 / NT;    // buckets per block
    int w = threadIdx.x >> 6;
    int lane = threadIdx.x & 63;
    int nslice = w % NT;
    int k = blockIdx.x * BPB + w / NT;
    if (k >= KK) return;
    int start = offsets[k];
    int n = offsets[k + 1] - start;
    if (n <= 0) return;
    int l15 = lane & 15;
    int lg = lane >> 4;  // 0..3

    // ---- B fragment: 16-column slice of W[k], hi+lo bf16 split ----
    const float* Wk = W + (size_t)k * (FIN * FOUT) + nslice * 16 + l15;
    bf16x8 Bh[KT], Bl[KT];
#pragma unroll
    for (int k0 = 0; k0 < KT; ++k0)
#pragma unroll
        for (int i = 0; i < 8; ++i) {
            float wv = Wk[(size_t)(k0 * 32 + lg * 8 + i) * FOUT];
            unsigned short hi = bf16rne(wv);
            unsigned short lo = bf16rne(wv - bf16tof(hi));
            Bh[k0][i] = (short)hi;
            Bl[k0][i] = (short)lo;
        }

    const int2* psb = pair_sb + start;
    const int* pdst = pair_dst + start;

    // ---- M-tile loop over pair rows ----
    for (int m0 = 0; m0 < n; m0 += 16) {
        int ra = m0 + l15;
        bool va = ra < n;
        int2 sb = psb[va ? ra : 0];
        float b = va ? __int_as_float(sb.y) : 0.0f;
        const float* xr = h + (size_t)sb.x * FIN + lg * 8;

        f32x4 acc = (f32x4){0.f, 0.f, 0.f, 0.f};
#pragma unroll
        for (int k0 = 0; k0 < KT; ++k0) {
            float4 v0 = *(const float4*)(xr + k0 * 32);
            float4 v1 = *(const float4*)(xr + k0 * 32 + 4);
            float xv[8] = {v0.x * b, v0.y * b, v0.z * b, v0.w * b,
                           v1.x * b, v1.y * b, v1.z * b, v1.w * b};
            bf16x8 Ah, Al;
#pragma unroll
            for (int i = 0; i < 8; ++i) {
                unsigned short hi = bf16rne(xv[i]);
                unsigned short lo = bf16rne(xv[i] - bf16tof(hi));
                Ah[i] = (short)hi;
                Al[i] = (short)lo;
            }
            acc = __builtin_amdgcn_mfma_f32_16x16x32_bf16(Ah, Bh[k0], acc, 0, 0, 0);
            acc = __builtin_amdgcn_mfma_f32_16x16x32_bf16(Ah, Bl[k0], acc, 0, 0, 0);
            acc = __builtin_amdgcn_mfma_f32_16x16x32_bf16(Al, Bh[k0], acc, 0, 0, 0);
        }

        // ---- scatter: D[(lg*4+j)][l15] ----
#pragma unroll
        for (int j = 0; j < 4; ++j) {
            int rm = m0 + lg * 4 + j;
            if (rm < n) {
                int d = pdst[rm];
                atomicAdd(&agg[(size_t)d * FOUT + nslice * 16 + l15], acc[j]);
            }
        }
    }
}

// Layer 1 (FIN=2, FOUT=32): direct loads, no staging.
__global__ __launch_bounds__(256) void conv_l1(
    const float* __restrict__ h, const float* __restrict__ W,
    const int* __restrict__ offsets, const int2* __restrict__ pair_sb,
    const int* __restrict__ pair_dst, float* __restrict__ agg) {
    int w = threadIdx.x >> 6;
    int lane = threadIdx.x & 63;
    int k = blockIdx.x * 4 + w;
    if (k >= KK) return;
    int start = offsets[k];
    int n = offsets[k + 1] - start;
    if (n <= 0) return;
    int o = lane & 31;
    int g = lane >> 5;
    const float* Wk = W + (size_t)k * 64;
    float w0 = Wk[o], w1 = Wk[32 + o];
    const float2* h2 = (const float2*)h;
    for (int r = g; r < n; r += 2) {
        int2 sb = pair_sb[start + r];
        float b = __int_as_float(sb.y);
        int dst = pair_dst[start + r];
        float2 xv = h2[sb.x];
        atomicAdd(&agg[(size_t)dst * 32 + o], b * (xv.x * w0 + xv.y * w1));
    }
}

// Layer 5 (FIN=32, FOUT=1): half-wave per row, shuffle reduce.
__global__ __launch_bounds__(256) void conv_f1(
    const float* __restrict__ h, const float* __restrict__ W,
    const int* __restrict__ offsets, const int2* __restrict__ pair_sb,
    const int* __restrict__ pair_dst, float* __restrict__ agg) {
    int w = threadIdx.x >> 6;
    int lane = threadIdx.x & 63;
    int k = blockIdx.x * 4 + w;
    if (k >= KK) return;
    int start = offsets[k];
    int n = offsets[k + 1] - start;
    if (n <= 0) return;
    int i = lane & 31;
    int g = lane >> 5;
    float wk = W[(size_t)k * 32 + i];
    for (int r = g; r < n; r += 2) {
        int2 sb = pair_sb[start + r];
        float b = __int_as_float(sb.y);
        int dst = pair_dst[start + r];
        float val = h[(size_t)sb.x * 32 + i] * wk * b;
#pragma unroll
        for (int d = 16; d >= 1; d >>= 1) val += __shfl_xor(val, d, 32);
        if (i == 0) atomicAdd(&agg[dst], val);
    }
}

// Node kernel: out = elu(agg + h@root + bias); also zeros agg[idx] (all NV*64)
// so the next conv needs no memset. Grid covers NV*64 threads.
template <int FIN, int FOUT>
__global__ void node_kernel(const float* __restrict__ h, float* __restrict__ agg,
                            const float* __restrict__ root, const float* __restrict__ bias,
                            float* __restrict__ hout) {
    int idx = blockIdx.x * blockDim.x + threadIdx.x;
    if (idx >= NV * 64) return;
    if (idx < NV * FOUT) {
        int n = idx / FOUT, o = idx % FOUT;
        float acc = agg[idx] + bias[o];
#pragma unroll
        for (int i = 0; i < FIN; ++i) acc += h[n * FIN + i] * root[i * FOUT + o];
        hout[idx] = acc > 0.0f ? acc : expm1f(acc);
    }
    agg[idx] = 0.0f;
}

extern "C" void kernel_launch(void* const* d_in, const int* in_sizes, int n_in,
                              void* d_out, int out_size, void* d_ws, size_t ws_size,
                              hipStream_t stream) {
    const float* x      = (const float*)d_in[0];
    const int*   ei     = (const int*)d_in[1];
    const float* pseudo = (const float*)d_in[2];
    const float* W1 = (const float*)d_in[3];
    const float* r1 = (const float*)d_in[4];
    const float* b1 = (const float*)d_in[5];
    const float* W2 = (const float*)d_in[6];
    const float* r2 = (const float*)d_in[7];
    const float* b2 = (const float*)d_in[8];
    const float* W3 = (const float*)d_in[9];
    const float* r3 = (const float*)d_in[10];
    const float* b3 = (const float*)d_in[11];
    const float* W4 = (const float*)d_in[12];
    const float* r4 = (const float*)d_in[13];
    const float* b4 = (const float*)d_in[14];
    const float* W5 = (const float*)d_in[15];
    const float* r5 = (const float*)d_in[16];
    const float* b5 = (const float*)d_in[17];

    char* ws = (char*)d_ws;
    size_t off = 0;
    auto alloc = [&](size_t bytes) {
        void* p = ws + off;
        off += (bytes + 255) & ~(size_t)255;
        return p;
    };
    int*   counts   = (int*)alloc(KK * sizeof(int));
    int*   offsets  = (int*)alloc((KK + 1) * sizeof(int));
    int*   cursor   = (int*)alloc(KK * sizeof(int));
    int2*  pair_sb  = (int2*)alloc((size_t)EV * 8 * sizeof(int2));
    int*   pair_dst = (int*)alloc((size_t)EV * 8 * sizeof(int));
    float* hA       = (float*)alloc((size_t)NV * 64 * sizeof(float));
    float* hB       = (float*)alloc((size_t)NV * 64 * sizeof(float));
    float* agg      = (float*)alloc((size_t)NV * 64 * sizeof(float));

    const int NGRID = (NV * 64 + 255) / 256;  // 2048 blocks

    prep_kernel<<<NGRID, 256, 0, stream>>>(x, hA, counts, agg);
    hist_kernel<<<(EV + 255) / 256, 256, 0, stream>>>(pseudo, counts);
    scan_kernel<<<1, 256, 0, stream>>>(counts, offsets, cursor);
    scatter_kernel<<<(EV + 255) / 256, 256, 0, stream>>>(pseudo, ei, cursor, pair_sb, pair_dst);

    // Layer 1: [N,2] -> [N,32]   (hA -> hB)
    conv_l1<<<(KK + 3) / 4, 256, 0, stream>>>(hA, W1, offsets, pair_sb, pair_dst, agg);
    node_kernel<2, 32><<<NGRID, 256, 0, stream>>>(hA, agg, r1, b1, hB);

    // Layer 2: [N,32] -> [N,64]  (hB -> hA)
    conv_v5<32, 64><<<KK, 256, 0, stream>>>(hB, W2, offsets, pair_sb, pair_dst, agg);
    node_kernel<32, 64><<<NGRID, 256, 0, stream>>>(hB, agg, r2, b2, hA);

    // Layer 3: [N,64] -> [N,64]  (hA -> hB)
    conv_v5<64, 64><<<KK, 256, 0, stream>>>(hA, W3, offsets, pair_sb, pair_dst, agg);
    node_kernel<64, 64><<<NGRID, 256, 0, stream>>>(hA, agg, r3, b3, hB);

    // Layer 4: [N,64] -> [N,32]  (hB -> hA)
    conv_v5<64, 32><<<(KK + 1) / 2, 256, 0, stream>>>(hB, W4, offsets, pair_sb, pair_dst, agg);
    node_kernel<64, 32><<<NGRID, 256, 0, stream>>>(hB, agg, r4, b4, hA);

    // Layer 5: [N,32] -> [N,1]   (hA -> d_out)
    conv_f1<<<(KK + 3) / 4, 256, 0, stream>>>(hA, W5, offsets, pair_sb, pair_dst, agg);
    node_kernel<32, 1><<<NGRID, 256, 0, stream>>>(hA, agg, r5, b5, (float*)d_out);
}